// Round 1
// baseline (251.128 us; speedup 1.0000x reference)
//
#include <hip/hip_runtime.h>
#include <hip/hip_bf16.h>

#define DIM 1024
#define STATE 256
#define BATCH 4
#define SEQ 4096
#define M_TOT (BATCH * SEQ)  // 16384

typedef short short8 __attribute__((ext_vector_type(8)));
typedef float f32x4 __attribute__((ext_vector_type(4)));

__device__ __forceinline__ unsigned short f2bf(float f) {
  unsigned int u = __float_as_uint(f);
  u += 0x7fff + ((u >> 16) & 1);  // RNE
  return (unsigned short)(u >> 16);
}

// ---------------- convert: x -> bf16, [B_w;D_w] -> bf16, C_w -> bf16 ----------
__global__ __launch_bounds__(256) void convert_kernel(
    const float* __restrict__ x, const float* __restrict__ Bw,
    const float* __restrict__ Dw, const float* __restrict__ Cw,
    unsigned short* __restrict__ xb, unsigned short* __restrict__ wcb,
    unsigned short* __restrict__ cwb) {
  const int bx = blockIdx.x;
  const int t = threadIdx.x;
  if (bx < 16384) {                    // x: 16384*1024 floats, 4/thread
    size_t i = ((size_t)bx * 256 + t) * 4;
    const float4 v = *(const float4*)(x + i);
    *(ushort4*)(xb + i) = make_ushort4(f2bf(v.x), f2bf(v.y), f2bf(v.z), f2bf(v.w));
  } else if (bx < 16384 + 1280) {      // Wc row per block
    int r = bx - 16384;
    int c = t * 4;
    const float* src = (r < STATE) ? (Bw + (size_t)r * DIM + c)
                                   : (Dw + (size_t)(r - STATE) * DIM + c);
    const float4 v = *(const float4*)src;
    *(ushort4*)(wcb + (size_t)r * DIM + c) =
        make_ushort4(f2bf(v.x), f2bf(v.y), f2bf(v.z), f2bf(v.w));
  } else {                             // C_w flat copy: 262144 elems / 256 blocks
    int r = bx - 16384 - 1280;
    size_t i = ((size_t)r * 256 + t) * 4;
    const float4 v = *(const float4*)(Cw + i);
    *(ushort4*)(cwb + i) = make_ushort4(f2bf(v.x), f2bf(v.y), f2bf(v.z), f2bf(v.w));
  }
}

// ---------------- bf16 MFMA GEMM, C[m,n] = sum_k A[m,k]*B[n,k] ----------------
// 128x128 tile, BK=32, 4 waves (2x2 of 64x64), 16x16x32 MFMA, global_load_lds.
// EPI=0: proj. n-tiles 0..1 -> Bu (+B_b), n-tiles 2..9 -> dout (+D_b)
// EPI=1: out.  dout = acc + C_b + dout
template <int EPI>
__global__ __launch_bounds__(256, 2) void gemm_bt(
    const unsigned short* __restrict__ A,  // [M][K] bf16
    const unsigned short* __restrict__ B,  // [N][K] bf16
    int K, int NTILES,
    float* __restrict__ out0,        // Bu [M][256] (EPI=0)
    float* __restrict__ dout,        // [M][1024]
    const float* __restrict__ bias0, // B_b
    const float* __restrict__ bias1) // D_b (EPI=0) / C_b (EPI=1)
{
  __shared__ unsigned short As[128 * 32];
  __shared__ unsigned short Bs[128 * 32];

  const int tid = threadIdx.x;
  const int wave = tid >> 6;
  const int lane = tid & 63;
  const int lr = lane & 15;   // row/col within 16
  const int lk = lane >> 4;   // k-quarter
  const int wr = wave >> 1;   // wave row 0..1
  const int wc = wave & 1;    // wave col 0..1

  const int ntile = blockIdx.x % NTILES;
  const int mtile = blockIdx.x / NTILES;
  const int m0 = mtile * 128;
  const int n0 = ntile * 128;

  const size_t ldab = (size_t)K * 2;  // row stride in bytes for A and B

  f32x4 acc[4][4];
#pragma unroll
  for (int i = 0; i < 4; ++i)
#pragma unroll
    for (int j = 0; j < 4; ++j) acc[i][j] = (f32x4){0.f, 0.f, 0.f, 0.f};

  const char* Abyte = (const char*)A;
  const char* Bbyte = (const char*)B;
  char* AsB = (char*)As;
  char* BsB = (char*)Bs;

  for (int k0 = 0; k0 < K; k0 += 32) {
#pragma unroll
    for (int i = 0; i < 2; ++i) {
      const int o = i * 4096 + tid * 16;  // byte offset in 8KB tile
      const int r = o >> 6;               // row (64B per row of 32 bf16)
      const int cb = o & 63;              // byte within row
      __builtin_amdgcn_global_load_lds(
          (const __attribute__((address_space(1))) void*)(Abyte + (size_t)(m0 + r) * ldab + (size_t)k0 * 2 + cb),
          (__attribute__((address_space(3))) void*)(AsB + i * 4096 + wave * 1024),
          16, 0, 0);
      __builtin_amdgcn_global_load_lds(
          (const __attribute__((address_space(1))) void*)(Bbyte + (size_t)(n0 + r) * ldab + (size_t)k0 * 2 + cb),
          (__attribute__((address_space(3))) void*)(BsB + i * 4096 + wave * 1024),
          16, 0, 0);
    }
    __syncthreads();  // drains vmcnt -> LDS tiles complete

    short8 af[4], bfr[4];
#pragma unroll
    for (int f = 0; f < 4; ++f) {
      af[f]  = *(const short8*)(AsB + (wr * 64 + f * 16 + lr) * 64 + lk * 16);
      bfr[f] = *(const short8*)(BsB + (wc * 64 + f * 16 + lr) * 64 + lk * 16);
    }
#pragma unroll
    for (int i = 0; i < 4; ++i)
#pragma unroll
      for (int j = 0; j < 4; ++j)
        acc[i][j] = __builtin_amdgcn_mfma_f32_16x16x32_bf16(af[i], bfr[j], acc[i][j], 0, 0, 0);
    __syncthreads();  // before next stage overwrites LDS
  }

#pragma unroll
  for (int fi = 0; fi < 4; ++fi)
#pragma unroll
    for (int fj = 0; fj < 4; ++fj)
#pragma unroll
      for (int j = 0; j < 4; ++j) {
        const int rg = m0 + wr * 64 + fi * 16 + lk * 4 + j;  // C/D: row=(lane>>4)*4+reg
        const int cg = n0 + wc * 64 + fj * 16 + lr;          //      col=lane&15
        const float v = acc[fi][fj][j];
        if (EPI == 0) {
          if (n0 < 256) {
            out0[(size_t)rg * STATE + cg] = v + bias0[cg];
          } else {
            const int c = cg - STATE;
            dout[(size_t)rg * DIM + c] = v + bias1[c];
          }
        } else {
          const float prev = dout[(size_t)rg * DIM + cg];
          dout[(size_t)rg * DIM + cg] = v + bias1[cg] + prev;
        }
      }
}

// ---------------- sequential scan: state = tanh(state*exp(A) + bu) -----------
// 4 blocks (one per batch) x 256 threads (one per state channel).
// tanh(z) = 1 - 2/(1+e^{2z});  t = state*(2*log2e*a) + bu*(2*log2e); e = 2^t
__global__ __launch_bounds__(256) void scan_kernel(
    const float* __restrict__ Bu, const float* __restrict__ A,
    unsigned short* __restrict__ states) {
  const int b = blockIdx.x;
  const int n = threadIdx.x;
  const float C2 = 2.8853900817779268f;  // 2*log2(e)
  const float a = __builtin_amdgcn_exp2f(A[n] * 1.4426950408889634f);
  const float a2 = a * C2;
  const float* p = Bu + (size_t)b * SEQ * STATE + n;
  unsigned short* q = states + (size_t)b * SEQ * STATE + n;
  constexpr int CH = 32;
  float cur[CH], nxt[CH];
#pragma unroll
  for (int j = 0; j < CH; ++j) cur[j] = p[(size_t)j * STATE];
  float state = 0.f;
  for (int c = 0; c < SEQ / CH; ++c) {
    if (c + 1 < SEQ / CH) {
      const float* pn = p + (size_t)(c + 1) * CH * STATE;
#pragma unroll
      for (int j = 0; j < CH; ++j) nxt[j] = pn[(size_t)j * STATE];
    }
    unsigned short* qc = q + (size_t)c * CH * STATE;
#pragma unroll
    for (int j = 0; j < CH; ++j) {
      const float t = fmaf(state, a2, cur[j] * C2);
      const float e = __builtin_amdgcn_exp2f(t);
      const float r = __builtin_amdgcn_rcpf(1.0f + e);
      state = fmaf(-2.0f, r, 1.0f);
      qc[(size_t)j * STATE] = f2bf(state);
    }
    if (c + 1 < SEQ / CH) {
#pragma unroll
      for (int j = 0; j < CH; ++j) cur[j] = nxt[j];
    }
  }
}

extern "C" void kernel_launch(void* const* d_in, const int* in_sizes, int n_in,
                              void* d_out, int out_size, void* d_ws, size_t ws_size,
                              hipStream_t stream) {
  const float* x  = (const float*)d_in[0];
  const float* A  = (const float*)d_in[1];
  const float* Bw = (const float*)d_in[2];
  const float* Bb = (const float*)d_in[3];
  const float* Cw = (const float*)d_in[4];
  const float* Cb = (const float*)d_in[5];
  const float* Dw = (const float*)d_in[6];
  const float* Db = (const float*)d_in[7];
  float* dout = (float*)d_out;

  char* ws = (char*)d_ws;
  unsigned short* xb  = (unsigned short*)(ws);              // 33,554,432 B
  unsigned short* wcb = (unsigned short*)(ws + 33554432);   //  2,621,440 B
  unsigned short* cwb = (unsigned short*)(ws + 36175872);   //    524,288 B
  float*          Bu  = (float*)         (ws + 36700160);   // 16,777,216 B
  unsigned short* stb = (unsigned short*)(ws + 53477376);   //  8,388,608 B -> 61,865,984 total

  // 1) dtype conversion
  convert_kernel<<<17920, 256, 0, stream>>>(x, Bw, Dw, Cw, xb, wcb, cwb);
  // 2) fused projections: Bu = x@B_w^T + B_b ; dout = x@D_w^T + D_b
  gemm_bt<0><<<128 * 10, 256, 0, stream>>>(xb, wcb, 1024, 10, Bu, dout, Bb, Db);
  // 3) recurrent scan -> states (bf16)
  scan_kernel<<<BATCH, 256, 0, stream>>>(Bu, A, stb);
  // 4) y = states@C_w^T + C_b + dout
  gemm_bt<1><<<128 * 8, 256, 0, stream>>>(stb, cwb, 256, 8, nullptr, dout, nullptr, Cb);
}

// Round 2
// 150.184 us; speedup vs baseline: 1.6721x; 1.6721x over previous
//
#include <hip/hip_runtime.h>
#include <hip/hip_bf16.h>

#define DIM 1024
#define STATE 256
#define BATCH 4
#define SEQ 4096
#define M_TOT (BATCH * SEQ)  // 16384

typedef short short8 __attribute__((ext_vector_type(8)));
typedef float f32x4 __attribute__((ext_vector_type(4)));

__device__ __forceinline__ unsigned short f2bf(float f) {
  unsigned int u = __float_as_uint(f);
  u += 0x7fff + ((u >> 16) & 1);  // RNE
  return (unsigned short)(u >> 16);
}

#define C2F 2.8853900817779268f   // 2*log2(e)
#define LOG2EF 1.4426950408889634f

// ---------------- convert: x -> bf16, [B_w;D_w] -> bf16, C_w -> bf16 ----------
// plus per-channel scan constants: bb2[n] = B_b[n]*C2 + C2*exp(A[n]),
//                                  mP2[n] = -2*C2*exp(A[n])
__global__ __launch_bounds__(256) void convert_kernel(
    const float* __restrict__ x, const float* __restrict__ Bw,
    const float* __restrict__ Dw, const float* __restrict__ Cw,
    const float* __restrict__ A, const float* __restrict__ Bb,
    unsigned short* __restrict__ xb, unsigned short* __restrict__ wcb,
    unsigned short* __restrict__ cwb, float* __restrict__ bb2,
    float* __restrict__ mP2) {
  const int bx = blockIdx.x;
  const int t = threadIdx.x;
  if (bx < 16384) {                    // x: 16384*1024 floats, 4/thread
    size_t i = ((size_t)bx * 256 + t) * 4;
    const float4 v = *(const float4*)(x + i);
    *(ushort4*)(xb + i) = make_ushort4(f2bf(v.x), f2bf(v.y), f2bf(v.z), f2bf(v.w));
  } else if (bx < 16384 + 1280) {      // Wc row per block
    int r = bx - 16384;
    int c = t * 4;
    const float* src = (r < STATE) ? (Bw + (size_t)r * DIM + c)
                                   : (Dw + (size_t)(r - STATE) * DIM + c);
    const float4 v = *(const float4*)src;
    *(ushort4*)(wcb + (size_t)r * DIM + c) =
        make_ushort4(f2bf(v.x), f2bf(v.y), f2bf(v.z), f2bf(v.w));
  } else if (bx < 16384 + 1280 + 256) {  // C_w flat copy
    int r = bx - 16384 - 1280;
    size_t i = ((size_t)r * 256 + t) * 4;
    const float4 v = *(const float4*)(Cw + i);
    *(ushort4*)(cwb + i) = make_ushort4(f2bf(v.x), f2bf(v.y), f2bf(v.z), f2bf(v.w));
  } else {                             // scan constants, one block
    const float P = C2F * __builtin_amdgcn_exp2f(A[t] * LOG2EF);
    bb2[t] = fmaf(Bb[t], C2F, P);
    mP2[t] = -2.0f * P;
  }
}

// ---------------- bf16 MFMA GEMM, C[m,n] = sum_k A[m,k]*B[n,k] ----------------
// 128x128 tile, BK=32, 4 waves (2x2 of 64x64), 16x16x32 MFMA, global_load_lds.
// EPI=0: proj. n-tiles 0..1 -> G = v*C2 + bb2  (scan-ready Bu)
//              n-tiles 2..9 -> dout = v + D_b
// EPI=1: out.  dout = acc + C_b + dout
template <int EPI>
__global__ __launch_bounds__(256, 2) void gemm_bt(
    const unsigned short* __restrict__ A,  // [M][K] bf16
    const unsigned short* __restrict__ B,  // [N][K] bf16
    int K, int NTILES,
    float* __restrict__ out0,        // G [M][256] (EPI=0)
    float* __restrict__ dout,        // [M][1024]
    const float* __restrict__ bias0, // bb2 (EPI=0)
    const float* __restrict__ bias1) // D_b (EPI=0) / C_b (EPI=1)
{
  __shared__ unsigned short As[128 * 32];
  __shared__ unsigned short Bs[128 * 32];

  const int tid = threadIdx.x;
  const int wave = tid >> 6;
  const int lane = tid & 63;
  const int lr = lane & 15;   // row/col within 16
  const int lk = lane >> 4;   // k-quarter
  const int wr = wave >> 1;   // wave row 0..1
  const int wc = wave & 1;    // wave col 0..1

  const int ntile = blockIdx.x % NTILES;
  const int mtile = blockIdx.x / NTILES;
  const int m0 = mtile * 128;
  const int n0 = ntile * 128;

  const size_t ldab = (size_t)K * 2;  // row stride in bytes for A and B

  f32x4 acc[4][4];
#pragma unroll
  for (int i = 0; i < 4; ++i)
#pragma unroll
    for (int j = 0; j < 4; ++j) acc[i][j] = (f32x4){0.f, 0.f, 0.f, 0.f};

  const char* Abyte = (const char*)A;
  const char* Bbyte = (const char*)B;
  char* AsB = (char*)As;
  char* BsB = (char*)Bs;

  for (int k0 = 0; k0 < K; k0 += 32) {
#pragma unroll
    for (int i = 0; i < 2; ++i) {
      const int o = i * 4096 + tid * 16;  // byte offset in 8KB tile
      const int r = o >> 6;               // row (64B per row of 32 bf16)
      const int cb = o & 63;              // byte within row
      __builtin_amdgcn_global_load_lds(
          (const __attribute__((address_space(1))) void*)(Abyte + (size_t)(m0 + r) * ldab + (size_t)k0 * 2 + cb),
          (__attribute__((address_space(3))) void*)(AsB + i * 4096 + wave * 1024),
          16, 0, 0);
      __builtin_amdgcn_global_load_lds(
          (const __attribute__((address_space(1))) void*)(Bbyte + (size_t)(n0 + r) * ldab + (size_t)k0 * 2 + cb),
          (__attribute__((address_space(3))) void*)(BsB + i * 4096 + wave * 1024),
          16, 0, 0);
    }
    __syncthreads();  // drains vmcnt -> LDS tiles complete

    short8 af[4], bfr[4];
#pragma unroll
    for (int f = 0; f < 4; ++f) {
      af[f]  = *(const short8*)(AsB + (wr * 64 + f * 16 + lr) * 64 + lk * 16);
      bfr[f] = *(const short8*)(BsB + (wc * 64 + f * 16 + lr) * 64 + lk * 16);
    }
#pragma unroll
    for (int i = 0; i < 4; ++i)
#pragma unroll
      for (int j = 0; j < 4; ++j)
        acc[i][j] = __builtin_amdgcn_mfma_f32_16x16x32_bf16(af[i], bfr[j], acc[i][j], 0, 0, 0);
    __syncthreads();  // before next stage overwrites LDS
  }

#pragma unroll
  for (int fi = 0; fi < 4; ++fi)
#pragma unroll
    for (int fj = 0; fj < 4; ++fj)
#pragma unroll
      for (int j = 0; j < 4; ++j) {
        const int rg = m0 + wr * 64 + fi * 16 + lk * 4 + j;  // C/D: row=(lane>>4)*4+reg
        const int cg = n0 + wc * 64 + fj * 16 + lr;          //      col=lane&15
        const float v = acc[fi][fj][j];
        if (EPI == 0) {
          if (n0 < 256) {
            out0[(size_t)rg * STATE + cg] = fmaf(v, C2F, bias0[cg]);
          } else {
            const int c = cg - STATE;
            dout[(size_t)rg * DIM + c] = v + bias1[c];
          }
        } else {
          const float prev = dout[(size_t)rg * DIM + cg];
          dout[(size_t)rg * DIM + cg] = v + bias1[cg] + prev;
        }
      }
}

// ---------------- chunked-parallel scan with warmup ---------------------------
// Recurrence in r-space: r = 1/(1+e),  e = 2^t,  t = fma(mP2, r, G_t)
// (state = 1 - 2r; G_t = bu*C2 + B_b*C2 + C2*exp(A) precomputed by GEMM1.)
// Chunks of 64 emitted steps; warmup W=192 from r=0.5 (state=0). Chunks with
// t0 <= 192 start at t=0 and are exact. Jacobian |exp(A)(1-s^2)| ~ 0.85/step
// -> warmup error ~1e-13 typical, <1e-4 worst-case.
__global__ __launch_bounds__(256) void scan_kernel(
    const float* __restrict__ G, const float* __restrict__ mP2arr,
    unsigned short* __restrict__ states) {
  const int b = blockIdx.x >> 6;      // 4 batches
  const int chunk = blockIdx.x & 63;  // 64 chunks
  const int n = threadIdx.x;
  const int t0 = chunk * 64;
  const int start = (t0 > 192) ? (t0 - 192) : 0;
  const int nw = t0 - start;          // warmup steps, multiple of 64
  const int total = nw + 64;

  const float* g = G + ((size_t)b * SEQ + start) * STATE + n;
  unsigned short* q = states + ((size_t)b * SEQ + start) * STATE + n;
  const float mP2 = mP2arr[n];

  float r = 0.5f;
  constexpr int CH = 16;
  float cur[CH], nxt[CH];
#pragma unroll
  for (int j = 0; j < CH; ++j) cur[j] = g[(size_t)j * STATE];

  const int NC = total / CH;
  for (int c = 0; c < NC; ++c) {
    if (c + 1 < NC) {
      const float* pn = g + (size_t)(c + 1) * CH * STATE;
#pragma unroll
      for (int j = 0; j < CH; ++j) nxt[j] = pn[(size_t)j * STATE];
    }
    if (c * CH >= nw) {  // emit phase (uniform branch; nw is a multiple of CH)
      unsigned short* qc = q + (size_t)c * CH * STATE;
#pragma unroll
      for (int j = 0; j < CH; ++j) {
        const float t = fmaf(mP2, r, cur[j]);
        const float e = __builtin_amdgcn_exp2f(t);
        r = __builtin_amdgcn_rcpf(1.0f + e);
        const float s = fmaf(-2.0f, r, 1.0f);  // off-chain
        qc[(size_t)j * STATE] = f2bf(s);
      }
    } else {             // warmup phase
#pragma unroll
      for (int j = 0; j < CH; ++j) {
        const float t = fmaf(mP2, r, cur[j]);
        const float e = __builtin_amdgcn_exp2f(t);
        r = __builtin_amdgcn_rcpf(1.0f + e);
      }
    }
    if (c + 1 < NC) {
#pragma unroll
      for (int j = 0; j < CH; ++j) cur[j] = nxt[j];
    }
  }
}

extern "C" void kernel_launch(void* const* d_in, const int* in_sizes, int n_in,
                              void* d_out, int out_size, void* d_ws, size_t ws_size,
                              hipStream_t stream) {
  const float* x  = (const float*)d_in[0];
  const float* A  = (const float*)d_in[1];
  const float* Bw = (const float*)d_in[2];
  const float* Bb = (const float*)d_in[3];
  const float* Cw = (const float*)d_in[4];
  const float* Cb = (const float*)d_in[5];
  const float* Dw = (const float*)d_in[6];
  const float* Db = (const float*)d_in[7];
  float* dout = (float*)d_out;

  char* ws = (char*)d_ws;
  unsigned short* xb  = (unsigned short*)(ws);              // 33,554,432 B
  unsigned short* wcb = (unsigned short*)(ws + 33554432);   //  2,621,440 B
  unsigned short* cwb = (unsigned short*)(ws + 36175872);   //    524,288 B
  float*          G   = (float*)         (ws + 36700160);   // 16,777,216 B
  unsigned short* stb = (unsigned short*)(ws + 53477376);   //  8,388,608 B
  float*          bb2 = (float*)         (ws + 61865984);   //      1,024 B
  float*          mP2 = (float*)         (ws + 61867008);   //      1,024 B -> 61,868,032 total

  // 1) dtype conversion + scan constants
  convert_kernel<<<17921, 256, 0, stream>>>(x, Bw, Dw, Cw, A, Bb, xb, wcb, cwb, bb2, mP2);
  // 2) fused projections: G = (x@B_w^T)*C2 + bb2 ; dout = x@D_w^T + D_b
  gemm_bt<0><<<128 * 10, 256, 0, stream>>>(xb, wcb, 1024, 10, G, dout, bb2, Db);
  // 3) chunked recurrent scan -> states (bf16)
  scan_kernel<<<BATCH * 64, 256, 0, stream>>>(G, mP2, stb);
  // 4) y = states@C_w^T + C_b + dout
  gemm_bt<1><<<128 * 8, 256, 0, stream>>>(stb, cwb, 256, 8, nullptr, dout, nullptr, Cb);
}

// Round 3
// 106.198 us; speedup vs baseline: 2.3647x; 1.4142x over previous
//
#include <hip/hip_runtime.h>
#include <hip/hip_bf16.h>

#define DIM 1024
#define STATE 256
#define BATCH 4
#define SEQ 4096
#define M_TOT (BATCH * SEQ)  // 16384

typedef short short8 __attribute__((ext_vector_type(8)));
typedef float f32x4 __attribute__((ext_vector_type(4)));

__device__ __forceinline__ unsigned short f2bf(float f) {
  unsigned int u = __float_as_uint(f);
  u += 0x7fff + ((u >> 16) & 1);  // RNE
  return (unsigned short)(u >> 16);
}

__device__ __forceinline__ void gl_lds16(const void* g, void* l) {
  __builtin_amdgcn_global_load_lds(
      (const __attribute__((address_space(1))) void*)g,
      (__attribute__((address_space(3))) void*)l, 16, 0, 0);
}

#define C2F 2.8853900817779268f   // 2*log2(e)
#define LOG2EF 1.4426950408889634f

// ---------------- convert ----------------------------------------------------
// x -> xb (bf16), Bw -> bwb [256][1024], [Cw|Dw] -> wob [1024][1280],
// scan consts bb2/mP2, out bias cbdb = Cb + Db.
__global__ __launch_bounds__(256) void convert_kernel(
    const float* __restrict__ x, const float* __restrict__ A,
    const float* __restrict__ Bw, const float* __restrict__ Bb,
    const float* __restrict__ Cw, const float* __restrict__ Cb,
    const float* __restrict__ Dw, const float* __restrict__ Db,
    unsigned short* __restrict__ xb, unsigned short* __restrict__ bwb,
    unsigned short* __restrict__ wob, float* __restrict__ bb2,
    float* __restrict__ mP2, float* __restrict__ cbdb) {
  const int bx = blockIdx.x;
  const int t = threadIdx.x;
  if (bx < 16384) {                    // x: 16384*1024 floats, 4/thread
    size_t i = ((size_t)bx * 256 + t) * 4;
    const float4 v = *(const float4*)(x + i);
    *(ushort4*)(xb + i) = make_ushort4(f2bf(v.x), f2bf(v.y), f2bf(v.z), f2bf(v.w));
  } else if (bx < 16384 + 256) {       // bwb row per block
    int r = bx - 16384;
    int c = t * 4;
    const float4 v = *(const float4*)(Bw + (size_t)r * DIM + c);
    *(ushort4*)(bwb + (size_t)r * DIM + c) =
        make_ushort4(f2bf(v.x), f2bf(v.y), f2bf(v.z), f2bf(v.w));
  } else if (bx < 16384 + 256 + 1024) { // wob row e = [Cw[e,:] | Dw[e,:]]
    int e = bx - 16384 - 256;
    if (t < 64) {
      const float4 v = *(const float4*)(Cw + (size_t)e * STATE + t * 4);
      *(ushort4*)(wob + (size_t)e * 1280 + t * 4) =
          make_ushort4(f2bf(v.x), f2bf(v.y), f2bf(v.z), f2bf(v.w));
    }
    const float4 v = *(const float4*)(Dw + (size_t)e * DIM + t * 4);
    *(ushort4*)(wob + (size_t)e * 1280 + 256 + t * 4) =
        make_ushort4(f2bf(v.x), f2bf(v.y), f2bf(v.z), f2bf(v.w));
  } else {                             // scan constants + out bias, one block
    const float P = C2F * __builtin_amdgcn_exp2f(A[t] * LOG2EF);
    bb2[t] = fmaf(Bb[t], C2F, P);
    mP2[t] = -2.0f * P;
#pragma unroll
    for (int k = 0; k < 4; ++k) {
      const int i = t * 4 + k;
      cbdb[i] = Cb[i] + Db[i];
    }
  }
}

// ---------------- gemm_G: G = (x @ Bw^T)*C2 + bb2  (m97 128^2 structure) -----
__global__ __launch_bounds__(256, 2) void gemm_G(
    const unsigned short* __restrict__ A,  // xb [M][1024]
    const unsigned short* __restrict__ B,  // bwb [256][1024]
    float* __restrict__ G,                 // [M][256]
    const float* __restrict__ bb2) {
  __shared__ unsigned short As[128 * 32];
  __shared__ unsigned short Bs[128 * 32];

  const int tid = threadIdx.x;
  const int wave = tid >> 6;
  const int lane = tid & 63;
  const int lr = lane & 15;
  const int lk = lane >> 4;
  const int wr = wave >> 1;
  const int wc = wave & 1;

  const int ntile = blockIdx.x & 1;   // 2 n-tiles
  const int mtile = blockIdx.x >> 1;  // 128 m-tiles
  const int m0 = mtile * 128;
  const int n0 = ntile * 128;

  f32x4 acc[4][4];
#pragma unroll
  for (int i = 0; i < 4; ++i)
#pragma unroll
    for (int j = 0; j < 4; ++j) acc[i][j] = (f32x4){0.f, 0.f, 0.f, 0.f};

  const char* Abyte = (const char*)A;
  const char* Bbyte = (const char*)B;
  char* AsB = (char*)As;
  char* BsB = (char*)Bs;

  for (int k0 = 0; k0 < 1024; k0 += 32) {
#pragma unroll
    for (int i = 0; i < 2; ++i) {
      const int o = i * 4096 + tid * 16;
      const int r = o >> 6;
      const int cb = o & 63;
      gl_lds16(Abyte + (size_t)(m0 + r) * 2048 + (size_t)k0 * 2 + cb,
               AsB + i * 4096 + wave * 1024);
      gl_lds16(Bbyte + (size_t)(n0 + r) * 2048 + (size_t)k0 * 2 + cb,
               BsB + i * 4096 + wave * 1024);
    }
    __syncthreads();

    short8 af[4], bfr[4];
#pragma unroll
    for (int f = 0; f < 4; ++f) {
      af[f]  = *(const short8*)(AsB + (wr * 64 + f * 16 + lr) * 64 + lk * 16);
      bfr[f] = *(const short8*)(BsB + (wc * 64 + f * 16 + lr) * 64 + lk * 16);
    }
#pragma unroll
    for (int i = 0; i < 4; ++i)
#pragma unroll
      for (int j = 0; j < 4; ++j)
        acc[i][j] = __builtin_amdgcn_mfma_f32_16x16x32_bf16(af[i], bfr[j], acc[i][j], 0, 0, 0);
    __syncthreads();
  }

#pragma unroll
  for (int fi = 0; fi < 4; ++fi)
#pragma unroll
    for (int fj = 0; fj < 4; ++fj)
#pragma unroll
      for (int j = 0; j < 4; ++j) {
        const int rg = m0 + wr * 64 + fi * 16 + lk * 4 + j;
        const int cg = n0 + wc * 64 + fj * 16 + lr;
        G[(size_t)rg * STATE + cg] = fmaf(acc[fi][fj][j], C2F, bb2[cg]);
      }
}

// ---------------- chunked-parallel scan with warmup ---------------------------
__global__ __launch_bounds__(256) void scan_kernel(
    const float* __restrict__ G, const float* __restrict__ mP2arr,
    unsigned short* __restrict__ states) {
  const int b = blockIdx.x >> 6;
  const int chunk = blockIdx.x & 63;
  const int n = threadIdx.x;
  const int t0 = chunk * 64;
  const int start = (t0 > 192) ? (t0 - 192) : 0;
  const int nw = t0 - start;
  const int total = nw + 64;

  const float* g = G + ((size_t)b * SEQ + start) * STATE + n;
  unsigned short* q = states + ((size_t)b * SEQ + start) * STATE + n;
  const float mP2 = mP2arr[n];

  float r = 0.5f;
  constexpr int CH = 16;
  float cur[CH], nxt[CH];
#pragma unroll
  for (int j = 0; j < CH; ++j) cur[j] = g[(size_t)j * STATE];

  const int NC = total / CH;
  for (int c = 0; c < NC; ++c) {
    if (c + 1 < NC) {
      const float* pn = g + (size_t)(c + 1) * CH * STATE;
#pragma unroll
      for (int j = 0; j < CH; ++j) nxt[j] = pn[(size_t)j * STATE];
    }
    if (c * CH >= nw) {
      unsigned short* qc = q + (size_t)c * CH * STATE;
#pragma unroll
      for (int j = 0; j < CH; ++j) {
        const float t = fmaf(mP2, r, cur[j]);
        const float e = __builtin_amdgcn_exp2f(t);
        r = __builtin_amdgcn_rcpf(1.0f + e);
        const float s = fmaf(-2.0f, r, 1.0f);
        qc[(size_t)j * STATE] = f2bf(s);
      }
    } else {
#pragma unroll
      for (int j = 0; j < CH; ++j) {
        const float t = fmaf(mP2, r, cur[j]);
        const float e = __builtin_amdgcn_exp2f(t);
        r = __builtin_amdgcn_rcpf(1.0f + e);
      }
    }
    if (c + 1 < NC) {
#pragma unroll
      for (int j = 0; j < CH; ++j) cur[j] = nxt[j];
    }
  }
}

// ---------------- gemm_out: dout = [states|x] @ [Cw|Dw]^T + (Cb+Db) ----------
// 256x256 tile, BK=32, K=1280 (40 tiles; ktile<8 -> stb, else xb).
// 8 waves (2M x 4N), per-wave 128x64. LDS: 4-slot ring of (16KB A + 16KB B),
// prefetch distance 3, counted vmcnt(8), per-phase barrier, setprio, XOR
// chunk swizzle c' = c ^ ((r>>1)&3) (pre-swizzled global source + swizzled
// ds_read; gload_lds dest stays linear).
__global__ __launch_bounds__(512, 2) void gemm_out(
    const unsigned short* __restrict__ stb,  // [16384][256] bf16
    const unsigned short* __restrict__ xb,   // [16384][1024] bf16
    const unsigned short* __restrict__ wob,  // [1024][1280] bf16
    const float* __restrict__ cbdb,          // [1024]
    float* __restrict__ dout)                // [16384][1024] f32
{
  __shared__ char lds[131072];  // 4 slots x 32KB (A 16KB + B 16KB)

  const int tid = threadIdx.x;
  const int wave = tid >> 6;
  const int lane = tid & 63;
  const int lr = lane & 15;
  const int lk = lane >> 4;
  const int wm = wave >> 2;  // 0..1
  const int wn = wave & 3;   // 0..3

  const int bs = ((blockIdx.x & 7) << 5) | (blockIdx.x >> 3);  // XCD swizzle (256%8==0)
  const int m0 = (bs >> 2) * 256;
  const int n0 = (bs & 3) * 256;

  const char* stbB = (const char*)stb;
  const char* xbB  = (const char*)xb;
  const char* wobB = (const char*)wob;

  f32x4 acc[8][4];
#pragma unroll
  for (int i = 0; i < 8; ++i)
#pragma unroll
    for (int j = 0; j < 4; ++j) acc[i][j] = (f32x4){0.f, 0.f, 0.f, 0.f};

  // ---- staging helpers (2 gload_lds each; source chunk pre-swizzled) ----
  auto stageA = [&](int kt) {
    const int sl = kt & 3;
    const char* abase;
    size_t astr;
    int akoff;
    if (kt < 8) { abase = stbB + (size_t)m0 * 512;  astr = 512;  akoff = kt * 64; }
    else        { abase = xbB  + (size_t)m0 * 2048; astr = 2048; akoff = (kt - 8) * 64; }
#pragma unroll
    for (int i = 0; i < 2; ++i) {
      const int s = i * 512 + tid;            // chunk slot (linear LDS order)
      const int r = s >> 2;
      const int c = (s & 3) ^ ((r >> 1) & 3); // inverse-swizzled source chunk
      gl_lds16(abase + (size_t)r * astr + akoff + c * 16,
               lds + sl * 32768 + i * 8192 + wave * 1024);
    }
  };
  auto stageB = [&](int kt) {
    const int sl = kt & 3;
#pragma unroll
    for (int i = 0; i < 2; ++i) {
      const int s = i * 512 + tid;
      const int r = s >> 2;
      const int c = (s & 3) ^ ((r >> 1) & 3);
      gl_lds16(wobB + (size_t)(n0 + r) * 2560 + kt * 64 + c * 16,
               lds + sl * 32768 + 16384 + i * 8192 + wave * 1024);
    }
  };

  // ---- prologue: stage tiles 0,1,2 (12 loads/thread in flight) ----
#pragma unroll
  for (int kt = 0; kt < 3; ++kt) { stageA(kt); stageB(kt); }

  short8 bfr[4];
  const int NT = 40;
  for (int t = 0; t < NT; ++t) {
    if (t < NT - 2)       asm volatile("s_waitcnt vmcnt(8)" ::: "memory");
    else if (t == NT - 2) asm volatile("s_waitcnt vmcnt(4)" ::: "memory");
    else                  asm volatile("s_waitcnt vmcnt(0)" ::: "memory");
    __builtin_amdgcn_s_barrier();

    const char* As = lds + (t & 3) * 32768;
    const char* Bs = As + 16384;

    // ---- phase 0: stage A(t+3) | read B-frags + A-frags(mh0) | 16 MFMA ----
    if (t + 3 < NT) stageA(t + 3);
    {
      short8 af[4];
#pragma unroll
      for (int fj = 0; fj < 4; ++fj) {
        const int r = wn * 64 + fj * 16 + lr;
        bfr[fj] = *(const short8*)(Bs + (r * 4 + (lk ^ ((r >> 1) & 3))) * 16);
      }
#pragma unroll
      for (int fi = 0; fi < 4; ++fi) {
        const int r = wm * 128 + fi * 16 + lr;
        af[fi] = *(const short8*)(As + (r * 4 + (lk ^ ((r >> 1) & 3))) * 16);
      }
      __builtin_amdgcn_s_setprio(1);
#pragma unroll
      for (int fi = 0; fi < 4; ++fi)
#pragma unroll
        for (int fj = 0; fj < 4; ++fj)
          acc[fi][fj] = __builtin_amdgcn_mfma_f32_16x16x32_bf16(af[fi], bfr[fj], acc[fi][fj], 0, 0, 0);
      __builtin_amdgcn_s_setprio(0);
    }
    __builtin_amdgcn_s_barrier();

    // ---- phase 1: stage B(t+3) | read A-frags(mh1) | 16 MFMA ----
    if (t + 3 < NT) stageB(t + 3);
    {
      short8 af[4];
#pragma unroll
      for (int fi = 0; fi < 4; ++fi) {
        const int r = wm * 128 + 64 + fi * 16 + lr;
        af[fi] = *(const short8*)(As + (r * 4 + (lk ^ ((r >> 1) & 3))) * 16);
      }
      __builtin_amdgcn_s_setprio(1);
#pragma unroll
      for (int fi = 0; fi < 4; ++fi)
#pragma unroll
        for (int fj = 0; fj < 4; ++fj)
          acc[4 + fi][fj] = __builtin_amdgcn_mfma_f32_16x16x32_bf16(af[fi], bfr[fj], acc[4 + fi][fj], 0, 0, 0);
      __builtin_amdgcn_s_setprio(0);
    }
  }

  // ---- epilogue: dout = acc + (Cb+Db) ----
#pragma unroll
  for (int fj = 0; fj < 4; ++fj) {
    const int col = n0 + wn * 64 + fj * 16 + lr;
    const float cb = cbdb[col];
#pragma unroll
    for (int m = 0; m < 8; ++m) {
      const int rowb = m0 + wm * 128 + (m >> 2) * 64 + (m & 3) * 16 + lk * 4;
#pragma unroll
      for (int j = 0; j < 4; ++j)
        dout[(size_t)(rowb + j) * DIM + col] = acc[m][fj][j] + cb;
    }
  }
}

extern "C" void kernel_launch(void* const* d_in, const int* in_sizes, int n_in,
                              void* d_out, int out_size, void* d_ws, size_t ws_size,
                              hipStream_t stream) {
  const float* x  = (const float*)d_in[0];
  const float* A  = (const float*)d_in[1];
  const float* Bw = (const float*)d_in[2];
  const float* Bb = (const float*)d_in[3];
  const float* Cw = (const float*)d_in[4];
  const float* Cb = (const float*)d_in[5];
  const float* Dw = (const float*)d_in[6];
  const float* Db = (const float*)d_in[7];
  float* dout = (float*)d_out;

  char* ws = (char*)d_ws;
  unsigned short* xb   = (unsigned short*)(ws);              // 33,554,432 B
  unsigned short* bwb  = (unsigned short*)(ws + 33554432);   //    524,288 B
  unsigned short* wob  = (unsigned short*)(ws + 34078720);   //  2,621,440 B
  float*          G    = (float*)         (ws + 36700160);   // 16,777,216 B
  unsigned short* stb  = (unsigned short*)(ws + 53477376);   //  8,388,608 B
  float*          bb2  = (float*)         (ws + 61865984);   //      1,024 B
  float*          mP2  = (float*)         (ws + 61867008);   //      1,024 B
  float*          cbdb = (float*)         (ws + 61868032);   //      4,096 B -> 61,872,128

  // 1) dtype conversion + constants
  convert_kernel<<<16384 + 256 + 1024 + 1, 256, 0, stream>>>(
      x, A, Bw, Bb, Cw, Cb, Dw, Db, xb, bwb, wob, bb2, mP2, cbdb);
  // 2) G = (x @ Bw^T)*C2 + bb2
  gemm_G<<<256, 256, 0, stream>>>(xb, bwb, G, bb2);
  // 3) chunked recurrent scan -> states (bf16)
  scan_kernel<<<BATCH * 64, 256, 0, stream>>>(G, mP2, stb);
  // 4) dout = [states|x] @ [Cw|Dw]^T + (Cb+Db)
  gemm_out<<<256, 512, 0, stream>>>(stb, xb, wob, cbdb, dout);
}

// Round 4
// 102.521 us; speedup vs baseline: 2.4495x; 1.0359x over previous
//
#include <hip/hip_runtime.h>
#include <hip/hip_bf16.h>

#define DIM 1024
#define STATE 256
#define BATCH 4
#define SEQ 4096
#define M_TOT (BATCH * SEQ)  // 16384

typedef short short8 __attribute__((ext_vector_type(8)));
typedef float f32x4 __attribute__((ext_vector_type(4)));

__device__ __forceinline__ unsigned short f2bf(float f) {
  unsigned int u = __float_as_uint(f);
  u += 0x7fff + ((u >> 16) & 1);  // RNE
  return (unsigned short)(u >> 16);
}

__device__ __forceinline__ void gl_lds16(const void* g, void* l) {
  __builtin_amdgcn_global_load_lds(
      (const __attribute__((address_space(1))) void*)g,
      (__attribute__((address_space(3))) void*)l, 16, 0, 0);
}

#define C2F 2.8853900817779268f   // 2*log2(e)
#define LOG2EF 1.4426950408889634f

// ---------------- convert ----------------------------------------------------
__global__ __launch_bounds__(256) void convert_kernel(
    const float* __restrict__ x, const float* __restrict__ A,
    const float* __restrict__ Bw, const float* __restrict__ Bb,
    const float* __restrict__ Cw, const float* __restrict__ Cb,
    const float* __restrict__ Dw, const float* __restrict__ Db,
    unsigned short* __restrict__ xb, unsigned short* __restrict__ bwb,
    unsigned short* __restrict__ wob, float* __restrict__ bb2,
    float* __restrict__ mP2, float* __restrict__ cbdb) {
  const int bx = blockIdx.x;
  const int t = threadIdx.x;
  if (bx < 16384) {                    // x: 16384*1024 floats, 4/thread
    size_t i = ((size_t)bx * 256 + t) * 4;
    const float4 v = *(const float4*)(x + i);
    *(ushort4*)(xb + i) = make_ushort4(f2bf(v.x), f2bf(v.y), f2bf(v.z), f2bf(v.w));
  } else if (bx < 16384 + 256) {       // bwb row per block
    int r = bx - 16384;
    int c = t * 4;
    const float4 v = *(const float4*)(Bw + (size_t)r * DIM + c);
    *(ushort4*)(bwb + (size_t)r * DIM + c) =
        make_ushort4(f2bf(v.x), f2bf(v.y), f2bf(v.z), f2bf(v.w));
  } else if (bx < 16384 + 256 + 1024) { // wob row e = [Cw[e,:] | Dw[e,:]]
    int e = bx - 16384 - 256;
    if (t < 64) {
      const float4 v = *(const float4*)(Cw + (size_t)e * STATE + t * 4);
      *(ushort4*)(wob + (size_t)e * 1280 + t * 4) =
          make_ushort4(f2bf(v.x), f2bf(v.y), f2bf(v.z), f2bf(v.w));
    }
    const float4 v = *(const float4*)(Dw + (size_t)e * DIM + t * 4);
    *(ushort4*)(wob + (size_t)e * 1280 + 256 + t * 4) =
        make_ushort4(f2bf(v.x), f2bf(v.y), f2bf(v.z), f2bf(v.w));
  } else {                             // scan constants + out bias, one block
    const float P = C2F * __builtin_amdgcn_exp2f(A[t] * LOG2EF);
    bb2[t] = fmaf(Bb[t], C2F, P);
    mP2[t] = -2.0f * P;
#pragma unroll
    for (int k = 0; k < 4; ++k) {
      const int i = t * 4 + k;
      cbdb[i] = Cb[i] + Db[i];
    }
  }
}

// ---------------- gemm_G: G = (x @ Bw^T)*C2 + bb2  (m97 128^2 structure) -----
__global__ __launch_bounds__(256, 2) void gemm_G(
    const unsigned short* __restrict__ A,  // xb [M][1024]
    const unsigned short* __restrict__ B,  // bwb [256][1024]
    float* __restrict__ G,                 // [M][256]
    const float* __restrict__ bb2) {
  __shared__ unsigned short As[128 * 32];
  __shared__ unsigned short Bs[128 * 32];

  const int tid = threadIdx.x;
  const int wave = tid >> 6;
  const int lane = tid & 63;
  const int lr = lane & 15;
  const int lk = lane >> 4;
  const int wr = wave >> 1;
  const int wc = wave & 1;

  const int ntile = blockIdx.x & 1;   // 2 n-tiles
  const int mtile = blockIdx.x >> 1;  // 128 m-tiles
  const int m0 = mtile * 128;
  const int n0 = ntile * 128;

  f32x4 acc[4][4];
#pragma unroll
  for (int i = 0; i < 4; ++i)
#pragma unroll
    for (int j = 0; j < 4; ++j) acc[i][j] = (f32x4){0.f, 0.f, 0.f, 0.f};

  const char* Abyte = (const char*)A;
  const char* Bbyte = (const char*)B;
  char* AsB = (char*)As;
  char* BsB = (char*)Bs;

  for (int k0 = 0; k0 < 1024; k0 += 32) {
#pragma unroll
    for (int i = 0; i < 2; ++i) {
      const int o = i * 4096 + tid * 16;
      const int r = o >> 6;
      const int cb = o & 63;
      gl_lds16(Abyte + (size_t)(m0 + r) * 2048 + (size_t)k0 * 2 + cb,
               AsB + i * 4096 + wave * 1024);
      gl_lds16(Bbyte + (size_t)(n0 + r) * 2048 + (size_t)k0 * 2 + cb,
               BsB + i * 4096 + wave * 1024);
    }
    __syncthreads();

    short8 af[4], bfr[4];
#pragma unroll
    for (int f = 0; f < 4; ++f) {
      af[f]  = *(const short8*)(AsB + (wr * 64 + f * 16 + lr) * 64 + lk * 16);
      bfr[f] = *(const short8*)(BsB + (wc * 64 + f * 16 + lr) * 64 + lk * 16);
    }
#pragma unroll
    for (int i = 0; i < 4; ++i)
#pragma unroll
      for (int j = 0; j < 4; ++j)
        acc[i][j] = __builtin_amdgcn_mfma_f32_16x16x32_bf16(af[i], bfr[j], acc[i][j], 0, 0, 0);
    __syncthreads();
  }

#pragma unroll
  for (int fi = 0; fi < 4; ++fi)
#pragma unroll
    for (int fj = 0; fj < 4; ++fj)
#pragma unroll
      for (int j = 0; j < 4; ++j) {
        const int rg = m0 + wr * 64 + fi * 16 + lk * 4 + j;
        const int cg = n0 + wc * 64 + fj * 16 + lr;
        G[(size_t)rg * STATE + cg] = fmaf(acc[fi][fj][j], C2F, bb2[cg]);
      }
}

// ---------------- chunked-parallel scan with warmup ---------------------------
__global__ __launch_bounds__(256) void scan_kernel(
    const float* __restrict__ G, const float* __restrict__ mP2arr,
    unsigned short* __restrict__ states) {
  const int b = blockIdx.x >> 6;
  const int chunk = blockIdx.x & 63;
  const int n = threadIdx.x;
  const int t0 = chunk * 64;
  const int start = (t0 > 192) ? (t0 - 192) : 0;
  const int nw = t0 - start;
  const int total = nw + 64;

  const float* g = G + ((size_t)b * SEQ + start) * STATE + n;
  unsigned short* q = states + ((size_t)b * SEQ + start) * STATE + n;
  const float mP2 = mP2arr[n];

  float r = 0.5f;
  constexpr int CH = 16;
  float cur[CH], nxt[CH];
#pragma unroll
  for (int j = 0; j < CH; ++j) cur[j] = g[(size_t)j * STATE];

  const int NC = total / CH;
  for (int c = 0; c < NC; ++c) {
    if (c + 1 < NC) {
      const float* pn = g + (size_t)(c + 1) * CH * STATE;
#pragma unroll
      for (int j = 0; j < CH; ++j) nxt[j] = pn[(size_t)j * STATE];
    }
    if (c * CH >= nw) {
      unsigned short* qc = q + (size_t)c * CH * STATE;
#pragma unroll
      for (int j = 0; j < CH; ++j) {
        const float t = fmaf(mP2, r, cur[j]);
        const float e = __builtin_amdgcn_exp2f(t);
        r = __builtin_amdgcn_rcpf(1.0f + e);
        const float s = fmaf(-2.0f, r, 1.0f);
        qc[(size_t)j * STATE] = f2bf(s);
      }
    } else {
#pragma unroll
      for (int j = 0; j < CH; ++j) {
        const float t = fmaf(mP2, r, cur[j]);
        const float e = __builtin_amdgcn_exp2f(t);
        r = __builtin_amdgcn_rcpf(1.0f + e);
      }
    }
    if (c + 1 < NC) {
#pragma unroll
      for (int j = 0; j < CH; ++j) cur[j] = nxt[j];
    }
  }
}

// ---------------- gemm_out: dout = [states|x] @ [Cw|Dw]^T + (Cb+Db) ----------
// 8-phase m201-style schedule. BM=BN=256, BK=64, K=1280 (20 tiles, 2/iter).
// 8 waves (2M x 4N), per-wave 128x64 out. LDS 128KB: A 2x32KB dbuf + B 2x32KB.
// Per phase: {ds_read subtile | stage 1 half-tile (2 gload_lds) | barrier |
// 16 MFMA (setprio) | [vmcnt(4) @P4/P8] | barrier}. Counted vmcnt, never 0
// except last-iter P4. XOR chunk swizzle c^(r&7) (pre-swizzled global source,
// linear gload_lds dest, swizzled ds_read).
#define VMC(N) asm volatile("s_waitcnt vmcnt(" #N ")" ::: "memory")

#define PH(TILE, Q, STG, VMST)                                                 \
  do {                                                                         \
    const char* As = lds + ((TILE) & 1) * 32768;                               \
    const char* Bs = lds + 65536 + ((TILE) & 1) * 32768;                       \
    if ((Q) == 0) {                                                            \
      _Pragma("unroll") for (int fj = 0; fj < 4; ++fj) {                       \
        const int r = wn * 64 + fj * 16 + lr;                                  \
        _Pragma("unroll") for (int kk = 0; kk < 2; ++kk)                       \
          bfr[fj][kk] = *(const short8*)(Bs + r * 128 +                        \
                                         (((kk * 4 + lk) ^ (r & 7)) << 4));    \
      }                                                                        \
    }                                                                          \
    short8 af[2][2];                                                           \
    _Pragma("unroll") for (int fl = 0; fl < 2; ++fl) {                         \
      const int r = wm * 128 + (Q) * 32 + fl * 16 + lr;                        \
      _Pragma("unroll") for (int kk = 0; kk < 2; ++kk)                         \
        af[fl][kk] = *(const short8*)(As + r * 128 +                           \
                                      (((kk * 4 + lk) ^ (r & 7)) << 4));       \
    }                                                                          \
    STG;                                                                       \
    __builtin_amdgcn_s_barrier();                                              \
    __builtin_amdgcn_s_setprio(1);                                             \
    _Pragma("unroll") for (int kk = 0; kk < 2; ++kk)                           \
      _Pragma("unroll") for (int fl = 0; fl < 2; ++fl)                         \
        _Pragma("unroll") for (int fj = 0; fj < 4; ++fj)                       \
          acc[(Q) * 2 + fl][fj] = __builtin_amdgcn_mfma_f32_16x16x32_bf16(     \
              af[fl][kk], bfr[fj][kk], acc[(Q) * 2 + fl][fj], 0, 0, 0);        \
    __builtin_amdgcn_s_setprio(0);                                             \
    VMST;                                                                      \
    __builtin_amdgcn_s_barrier();                                              \
  } while (0)

__global__ __launch_bounds__(512, 2) void gemm_out(
    const unsigned short* __restrict__ stb,  // [16384][256] bf16
    const unsigned short* __restrict__ xb,   // [16384][1024] bf16
    const unsigned short* __restrict__ wob,  // [1024][1280] bf16
    const float* __restrict__ cbdb,          // [1024]
    float* __restrict__ dout)                // [16384][1024] f32
{
  __shared__ char lds[131072];  // A: 2x32KB @0, B: 2x32KB @65536

  const int tid = threadIdx.x;
  const int wave = tid >> 6;
  const int lane = tid & 63;
  const int lr = lane & 15;
  const int lk = lane >> 4;
  const int wm = wave >> 2;  // 0..1
  const int wn = wave & 3;   // 0..3

  const int bs = ((blockIdx.x & 7) << 5) | (blockIdx.x >> 3);  // XCD swizzle (256%8==0)
  const int m0 = (bs >> 2) * 256;
  const int n0 = (bs & 3) * 256;

  const char* stbB = (const char*)stb;
  const char* xbB  = (const char*)xb;
  const char* wobB = (const char*)wob;

  f32x4 acc[8][4];
#pragma unroll
  for (int i = 0; i < 8; ++i)
#pragma unroll
    for (int j = 0; j < 4; ++j) acc[i][j] = (f32x4){0.f, 0.f, 0.f, 0.f};

  // stage one half-tile (128 rows x 64 cols bf16 = 16KB = 2 gload_lds/thread)
  auto stageA = [&](int kt, int h) {
    if (kt >= 20) return;
    const char* base;
    size_t str;
    size_t colb;
    if (kt < 4) { base = stbB; str = 512;  colb = (size_t)kt * 128; }
    else        { base = xbB;  str = 2048; colb = (size_t)(kt - 4) * 128; }
    base += (size_t)m0 * str;
#pragma unroll
    for (int i2 = 0; i2 < 2; ++i2) {
      const int s = i2 * 512 + tid;
      const int r = s >> 3;                    // 0..127 within half
      const int cl = (s & 7) ^ (r & 7);        // inverse-swizzled source chunk
      gl_lds16(base + (size_t)(h * 128 + r) * str + colb + cl * 16,
               lds + ((kt & 1) * 32768) + h * 16384 + i2 * 8192 + wave * 1024);
    }
  };
  auto stageB = [&](int kt, int h) {
    if (kt >= 20) return;
#pragma unroll
    for (int i2 = 0; i2 < 2; ++i2) {
      const int s = i2 * 512 + tid;
      const int r = s >> 3;
      const int cl = (s & 7) ^ (r & 7);
      gl_lds16(wobB + (size_t)(n0 + h * 128 + r) * 2560 + (size_t)kt * 128 + cl * 16,
               lds + 65536 + ((kt & 1) * 32768) + h * 16384 + i2 * 8192 + wave * 1024);
    }
  };

  // ---- prologue: A(0), B(0), B(1) = 6 half-tiles (12 loads/wave) ----
  stageA(0, 0); stageA(0, 1);
  stageB(0, 0); stageB(0, 1);
  stageB(1, 0); stageB(1, 1);
  VMC(4);  // A(0),B(0) complete; B(1)'s 4 loads may fly
  __builtin_amdgcn_s_barrier();

  short8 bfr[4][2];
  for (int i = 0; i < 10; ++i) {
    const int e = 2 * i, o = e + 1;
    PH(e, 0, stageA(o, 0), );
    PH(e, 1, stageA(o, 1), );
    PH(e, 2, stageB(e + 2, 0), );
    PH(e, 3, stageB(e + 2, 1), if (i == 9) { VMC(0); } else { VMC(4); });
    PH(o, 0, stageA(e + 2, 0), );
    PH(o, 1, stageA(e + 2, 1), );
    PH(o, 2, stageB(o + 2, 0), );
    PH(o, 3, stageB(o + 2, 1), VMC(4));
  }

  // ---- epilogue: dout = acc + (Cb+Db) ----
#pragma unroll
  for (int fj = 0; fj < 4; ++fj) {
    const int col = n0 + wn * 64 + fj * 16 + lr;
    const float cb = cbdb[col];
#pragma unroll
    for (int m = 0; m < 8; ++m) {
      const int rowb = m0 + wm * 128 + m * 16 + lk * 4;
#pragma unroll
      for (int j = 0; j < 4; ++j)
        dout[(size_t)(rowb + j) * DIM + col] = acc[m][fj][j] + cb;
    }
  }
}

extern "C" void kernel_launch(void* const* d_in, const int* in_sizes, int n_in,
                              void* d_out, int out_size, void* d_ws, size_t ws_size,
                              hipStream_t stream) {
  const float* x  = (const float*)d_in[0];
  const float* A  = (const float*)d_in[1];
  const float* Bw = (const float*)d_in[2];
  const float* Bb = (const float*)d_in[3];
  const float* Cw = (const float*)d_in[4];
  const float* Cb = (const float*)d_in[5];
  const float* Dw = (const float*)d_in[6];
  const float* Db = (const float*)d_in[7];
  float* dout = (float*)d_out;

  char* ws = (char*)d_ws;
  unsigned short* xb   = (unsigned short*)(ws);              // 33,554,432 B
  unsigned short* bwb  = (unsigned short*)(ws + 33554432);   //    524,288 B
  unsigned short* wob  = (unsigned short*)(ws + 34078720);   //  2,621,440 B
  float*          G    = (float*)         (ws + 36700160);   // 16,777,216 B
  unsigned short* stb  = (unsigned short*)(ws + 53477376);   //  8,388,608 B
  float*          bb2  = (float*)         (ws + 61865984);   //      1,024 B
  float*          mP2  = (float*)         (ws + 61867008);   //      1,024 B
  float*          cbdb = (float*)         (ws + 61868032);   //      4,096 B -> 61,872,128

  // 1) dtype conversion + constants
  convert_kernel<<<16384 + 256 + 1024 + 1, 256, 0, stream>>>(
      x, A, Bw, Bb, Cw, Cb, Dw, Db, xb, bwb, wob, bb2, mP2, cbdb);
  // 2) G = (x @ Bw^T)*C2 + bb2
  gemm_G<<<256, 256, 0, stream>>>(xb, bwb, G, bb2);
  // 3) chunked recurrent scan -> states (bf16)
  scan_kernel<<<BATCH * 64, 256, 0, stream>>>(G, mP2, stb);
  // 4) dout = [states|x] @ [Cw|Dw]^T + (Cb+Db)
  gemm_out<<<256, 512, 0, stream>>>(stb, xb, wob, cbdb, dout);
}